// Round 7
// baseline (322.603 us; speedup 1.0000x reference)
//
#include <hip/hip_runtime.h>
#include <math.h>

#define B_TOT 4096
#define TE 168
#define TD 24
#define NWG 256          // 16 batches per WG; 768 threads -> 3 waves/SIMD
#define HSTR 72          // padded f16 row stride (144 B, 16B-aligned)

typedef _Float16 f16;
typedef __attribute__((ext_vector_type(8))) _Float16 f16x8;
typedef __attribute__((ext_vector_type(4))) float f32x4;

// Activation pre-scaling folded into weights/biases:
//   i,f,o: w *= -log2(e)  -> E = exp2(y) = e^{-x}; sigmoid = 1/(1+E)
//   g:     w *= 2*log2(e) -> E = e^{2x};  tanh = (E-1)/(E+1)
#define SCL_S (-1.4426950408889634f)
#define SCL_G (2.885390081777927f)

// ---------------------------------------------------------------------------
// Pack weights into MFMA B-fragment order, f16, pre-scaled per gate:
//   pk[w][l][q][c][lane][j] = scale_q * Wcomb_l[q*64+w*16+(lane&15)][c*32+(lane>>4)*8+j]
//   l=0 (K=96):  k<8 -> Wih0; 8..31 -> 0; 32..95 -> Whh0[k-32]  (c=3 all zero)
//   l=1 (K=128): k<64 -> Wih1 (input h0); else Whh1[k-64] (recurrent h1)
//   l=2 (K=128): k<64 -> Wih2 (input h1); else Whh2[k-64] (recurrent h2)
// ---------------------------------------------------------------------------
__global__ __launch_bounds__(256) void pack_kernel(
    const float* __restrict__ Wih0, const float* __restrict__ Whh0,
    const float* __restrict__ Wih1, const float* __restrict__ Whh1,
    const float* __restrict__ Wih2, const float* __restrict__ Whh2,
    f16* __restrict__ pk)
{
    int idx = blockIdx.x * 256 + threadIdx.x;   // 0 .. 98303
    int j = idx & 7;
    int t = idx >> 3;
    int ln = t & 63; t >>= 6;
    int c  = t & 3;  t >>= 2;
    int q  = t & 3;  t >>= 2;
    int l  = t % 3;
    int w  = t / 3;
    int row = q * 64 + w * 16 + (ln & 15);
    int k   = c * 32 + ((ln >> 4) << 3) + j;
    float val = 0.f;
    if (l == 0) {
        if (k < 8)                 val = Wih0[row * 8 + k];
        else if (k >= 32 && k < 96) val = Whh0[row * 64 + (k - 32)];
    } else if (l == 1) {
        val = (k < 64) ? Wih1[row * 64 + k] : Whh1[row * 64 + (k - 64)];
    } else {
        val = (k < 64) ? Wih2[row * 64 + k] : Whh2[row * 64 + (k - 64)];
    }
    const float sc = (q == 2) ? SCL_G : SCL_S;
    pk[idx] = (f16)(val * sc);
}

// softplus via 2 HW trans ops (no libm log1pf):
//   softplus(x) = max(x,0) + ln2 * log2(1 + 2^(-|x|*log2e))
__device__ __forceinline__ float softplusf(float x) {
    float t = fabsf(x) * 1.4426950408889634f;
    float E = __builtin_amdgcn_exp2f(-t);
    float L = __builtin_amdgcn_logf(1.f + E);      // log2
    return fmaxf(x, 0.f) + 0.6931471805599453f * L;
}

// ---------------------------------------------------------------------------
// 256 WGs x 768 threads (12 waves); WG owns 16 batches (M=16 tile dense).
// One LAYER per wave role: role = tid>>8 -> 0:L0, 1:L1, 2:L2; within a role,
// wave wv owns hid block wv*16..+16.
//
// R14: LAGGED pipeline over a 4-slot h ring (slot = timestep & 3).
//   role0 @ round k computes L0(t=k); role1: L1(t=k-2); role2: L2(t=k-4).
//   Layer-handoff distance = 2 rounds -> each consumer PREFETCHES its
//   input-layer fragments (h0 for L1, h1 for L2) one round early into held
//   regs hfa/hfb (8 VGPR). At round k: issue sibling ds_reads, then fire
//   the input-half MFMAs from hfa/hfb with ZERO wait (reads land under
//   them). Read latency leaves the critical path. Sibling recurrence stays
//   distance-1 (structural). No acc lives across any barrier (R11 lesson).
//   172 rounds total (+2 pipeline fill). 1 RBAR (lgkm-only) per round.
//   Decoder: same 4-slot ring, 3 RBAR/step, in-wave redundant head (R13).
// __launch_bounds__(768,2): VGPR cap 128; 12-wave WG needs 3 waves/SIMD,
// HW allows 4 at <=128 VGPR (R12 established cap = 256/arg2).
// ---------------------------------------------------------------------------
__global__ __launch_bounds__(768, 2) void lstm_kernel(
    const float* __restrict__ enc_x, const float* __restrict__ enc_z,
    const float* __restrict__ dec_x, const float* __restrict__ v,
    const float* __restrict__ eps,   const f16* __restrict__ pk,
    const float* __restrict__ b0, const float* __restrict__ b1,
    const float* __restrict__ b2,
    const float* __restrict__ w_m, const float* __restrict__ b_m,
    const float* __restrict__ w_a, const float* __restrict__ b_a,
    float* __restrict__ out)
{
    const int tid  = threadIdx.x;
    const int lane = tid & 63;
    const int wv   = (tid >> 6) & 3;    // hid block within role
    const int role = tid >> 8;          // 0:L0, 1:L1, 2:L2
    const int bg   = blockIdx.x * 16;
    const int m16  = lane & 15;
    const int quad = lane >> 4;

    __shared__ f16 hbuf[4][3][16][HSTR];   // [slot][layer][batch][hid]

    // ---- zero LDS (all 4 slots: slot 3 = h(-1) = 0 for t=0 reads) ----
    {
        uint* hz = (uint*)&hbuf[0][0][0][0];
        const int HW = 4 * 3 * 16 * HSTR / 2;   // 6912 words
        for (int i = tid; i < HW; i += 768) hz[i] = 0u;
    }

    // ---- weight fragments: this wave's layer only; register-resident ----
    f16x8 wgt[4][4];                    // [chunk][gate]
#define PKOFF(l, q, c) ((((((size_t)wv * 3 + (l)) * 4 + (q)) * 4 + (c)) * 64 + lane) * 8)
    {
        const f16* pkr = pk + PKOFF(role, 0, 0);
#pragma unroll
        for (int q = 0; q < 4; ++q)
#pragma unroll
            for (int c = 0; c < 4; ++c)
                wgt[c][q] = *(const f16x8*)(pkr + (q * 4 + c) * 64 * 8);
    }
#undef PKOFF

    const int hid_self = wv * 16 + m16;
    // bias splats (pre-scaled) for this wave's layer; MFMA C operand
    f32x4 bsp[4];
    {
        const float* bp = (role == 0) ? b0 : (role == 1) ? b1 : b2;
#pragma unroll
        for (int q = 0; q < 4; ++q) {
            const float sc = (q == 2) ? SCL_G : SCL_S;
            float bv = bp[q * 64 + hid_self] * sc;
            bsp[q] = (f32x4){bv, bv, bv, bv};
        }
    }

    f16* hb = &hbuf[0][0][0][0];
    const int aoff = m16 * HSTR + quad * 8;
    float cst[4] = {};                  // cell state for this wave's layer
    f16x8 hfa = {}, hfb = {};           // held input fragments (prefetched);
                                        // role0: hfa = x fragment

// Raw barrier: drain only LDS ops (lgkmcnt); globals stay in flight.
#define RBAR                                                                  \
    {                                                                         \
        asm volatile("s_waitcnt lgkmcnt(0)" ::: "memory");                    \
        __builtin_amdgcn_s_barrier();                                         \
        asm volatile("" ::: "memory");                                        \
    }

#define PRIO_UP __builtin_amdgcn_s_setprio(1)
#define PRIO_DN __builtin_amdgcn_s_setprio(0)

#define HB(s, l) (hb + ((s) * 3 + (l)) * (16 * HSTR))
#define MFMA16(af, bf, cf) __builtin_amdgcn_mfma_f32_16x16x32_f16(af, bf, cf, 0, 0, 0)

#define MM_R(P, areg, wi)                                                     \
    {                                                                         \
        P##0 = MFMA16(areg, wgt[wi][0], bsp[0]);                              \
        P##1 = MFMA16(areg, wgt[wi][1], bsp[1]);                              \
        P##2 = MFMA16(areg, wgt[wi][2], bsp[2]);                              \
        P##3 = MFMA16(areg, wgt[wi][3], bsp[3]);                              \
    }
#define MM_RACC(P, areg, wi)                                                  \
    {                                                                         \
        P##0 = MFMA16(areg, wgt[wi][0], P##0);                                \
        P##1 = MFMA16(areg, wgt[wi][1], P##1);                                \
        P##2 = MFMA16(areg, wgt[wi][2], P##2);                                \
        P##3 = MFMA16(areg, wgt[wi][3], P##3);                                \
    }

// Merged-rcp cell: sigmoid(f)=pig*R, i*g=(Eg-1)*ef1*R, R=rcp(pig*ef1);
// o*tanh(c)=(Ec-1)*rcp((1+Eo)(1+Ec)). 5 exp2 + 2 rcp per output.
// C/D layout (m89): lane -> col(hid)=m16, rows(batch)=quad*4+r.
#define CELL(P, lh, SS)                                                       \
    {                                                                         \
        f16* hw = HB(SS, lh) + hid_self;                                      \
        _Pragma("unroll")                                                     \
        for (int r = 0; r < 4; ++r) {                                         \
            float Ei = __builtin_amdgcn_exp2f(P##0[r]);                       \
            float Ef = __builtin_amdgcn_exp2f(P##1[r]);                       \
            float Eg = __builtin_amdgcn_exp2f(P##2[r]);                       \
            float Eo = __builtin_amdgcn_exp2f(P##3[r]);                       \
            float ef1 = 1.f + Ef;                                             \
            float pig = (1.f + Ei) * (1.f + Eg);                              \
            float R   = __builtin_amdgcn_rcpf(pig * ef1);                     \
            float fv  = pig * R;                                              \
            float ig  = (Eg - 1.f) * ef1 * R;                                 \
            float cn  = fmaf(fv, cst[r], ig);                                 \
            cst[r] = cn;                                                      \
            float Ec  = __builtin_amdgcn_exp2f(cn * SCL_G);                   \
            float Roc = __builtin_amdgcn_rcpf((1.f + Eo) * (1.f + Ec));       \
            hw[(quad * 4 + r) * HSTR] = (f16)((Ec - 1.f) * Roc);              \
        }                                                                     \
    }

    // ---------------- encoder (lagged pipeline, 1 RBAR/round) ----------------
    const float* xp = enc_x + (size_t)(bg + m16) * (TE * 8);
    if (role == 0) {
        f32x4 xa = *(const f32x4*)xp;
        f32x4 xb = *(const f32x4*)(xp + 4);
#pragma unroll
        for (int j = 0; j < 4; ++j) { hfa[j] = (f16)xa[j]; hfa[4 + j] = (f16)xb[j]; }
    }

// Round k, S = k&3 (compile-time). Slots (derived from lags, all & 3):
//   role0 (t=k):    sib h0 read (S+3), write h0 S
//   role1 (t=k-2):  held h0(t) [prefetched k-1], sib h1 read (S+1),
//                   write h1 (S+2), prefetch h0(t+1) from (S+3)
//   role2 (t=k-4):  held h1(t), sib h2 read (S+3), write h2 S,
//                   prefetch h1(t+1) from (S+1)
// Prefetch is issued AFTER the old hfa/hfb are consumed (WAR) and lands
// under CELL; RBAR's lgkm drain covers it.
#define ROUND(S, D0, D1, P1, D2, P2, T0)                                      \
    {                                                                         \
        RBAR;                                                                 \
        f32x4 a0, a1, a2, a3;                                                 \
        if (role == 0) {                                                      \
            if (D0) {                                                         \
                const f16* sp = HB((S + 3) & 3, 0) + aoff;                    \
                f16x8 s0 = *(const f16x8*)sp;                                 \
                f16x8 s1 = *(const f16x8*)(sp + 32);                          \
                PRIO_UP;                                                      \
                MM_R(a, hfa, 0);                                              \
                MM_RACC(a, s0, 1);                                            \
                MM_RACC(a, s1, 2);                                            \
                PRIO_DN;                                                      \
                f32x4 xta = {}, xtb = {};                                     \
                if ((T0) + 1 < TE) {                                          \
                    xta = *(const f32x4*)(xp + (size_t)((T0) + 1) * 8);       \
                    xtb = *(const f32x4*)(xp + (size_t)((T0) + 1) * 8 + 4);   \
                }                                                             \
                CELL(a, 0, S);                                                \
                if ((T0) + 1 < TE) {                                          \
                    _Pragma("unroll")                                         \
                    for (int j = 0; j < 4; ++j) {                             \
                        hfa[j] = (f16)xta[j]; hfa[4 + j] = (f16)xtb[j];       \
                    }                                                         \
                }                                                             \
            }                                                                 \
        } else if (role == 1) {                                               \
            if (D1) {                                                         \
                const f16* sp = HB((S + 1) & 3, 1) + aoff;                    \
                f16x8 s0 = *(const f16x8*)sp;                                 \
                f16x8 s1 = *(const f16x8*)(sp + 32);                          \
                PRIO_UP;                                                      \
                MM_R(a, hfa, 0);                                              \
                MM_RACC(a, hfb, 1);                                           \
                MM_RACC(a, s0, 2);                                            \
                MM_RACC(a, s1, 3);                                            \
                PRIO_DN;                                                      \
            }                                                                 \
            if (P1) {                                                         \
                const f16* pp = HB((S + 3) & 3, 0) + aoff;                    \
                hfa = *(const f16x8*)pp;                                      \
                hfb = *(const f16x8*)(pp + 32);                               \
            }                                                                 \
            if (D1) CELL(a, 1, (S + 2) & 3);                                  \
        } else {                                                              \
            if (D2) {                                                         \
                const f16* sp = HB((S + 3) & 3, 2) + aoff;                    \
                f16x8 s0 = *(const f16x8*)sp;                                 \
                f16x8 s1 = *(const f16x8*)(sp + 32);                          \
                PRIO_UP;                                                      \
                MM_R(a, hfa, 0);                                              \
                MM_RACC(a, hfb, 1);                                           \
                MM_RACC(a, s0, 2);                                            \
                MM_RACC(a, s1, 3);                                            \
                PRIO_DN;                                                      \
            }                                                                 \
            if (P2) {                                                         \
                const f16* pp = HB((S + 1) & 3, 1) + aoff;                    \
                hfa = *(const f16x8*)pp;                                      \
                hfb = *(const f16x8*)(pp + 32);                               \
            }                                                                 \
            if (D2) CELL(a, 2, S);                                            \
        }                                                                     \
    }

    // fill: k=0..3
    ROUND(0, 1, 0, 0, 0, 0, 0)           // k=0:  L0(0)
    ROUND(1, 1, 0, 1, 0, 0, 1)           // k=1:  L0(1); pf h0(0)
    ROUND(2, 1, 1, 1, 0, 0, 2)           // k=2:  L0(2), L1(0); pf h0(1)
    ROUND(3, 1, 1, 1, 0, 1, 3)           // k=3:  L0(3), L1(1); pf h0(2), h1(0)
    // dense: k=4..167 (all active)
    for (int k = 4; k < 168; k += 4) {
        ROUND(0, 1, 1, 1, 1, 1, k)
        ROUND(1, 1, 1, 1, 1, 1, k + 1)
        ROUND(2, 1, 1, 1, 1, 1, k + 2)
        ROUND(3, 1, 1, 1, 1, 1, k + 3)
    }
    // drain: k=168..171
    ROUND(0, 0, 1, 1, 1, 1, 168)         // L1(166), L2(164); pf h0(167), h1(165)
    ROUND(1, 0, 1, 0, 1, 1, 169)         // L1(167), L2(165); pf h1(166)
    ROUND(2, 0, 0, 0, 1, 1, 170)         // L2(166); pf h1(167)
    ROUND(3, 0, 0, 0, 1, 0, 171)         // L2(167)
    // exit: h0(167), h1(167), h2(167) all in slot 167&3 = 3

    // ---------------- decoder (serial; z feedback; 3 RBAR/step) ----------------
    // role0 per-lane state for batch m16 (redundant across quads & waves).
    float vf = 0.f, rvf = 0.f, bmv = 0.f, bav = 0.f, zn = 0.f, ep_hold = 0.f;
    float dxr[7] = {};
    f32x4 wmv4[4] = {}, wav4[4] = {};   // w_m/w_a for hid quad*16..+16
    if (role == 0) {
        vf  = v[bg + m16];
        rvf = 1.0f / vf;
        bmv = b_m[0]; bav = b_a[0];
        zn  = enc_z[(size_t)(bg + m16) * TE + (TE - 1)] * rvf;
        ep_hold = eps[(size_t)(bg + m16) * TD + 0];
#pragma unroll
        for (int j = 0; j < 7; ++j)
            dxr[j] = dec_x[((size_t)(bg + m16) * TD + 0) * 7 + j];
#pragma unroll
        for (int i = 0; i < 4; ++i) {
            wmv4[i] = *(const f32x4*)(w_m + quad * 16 + 4 * i);
            wav4[i] = *(const f32x4*)(w_a + quad * 16 + 4 * i);
        }
    }

// In-wave redundant head for time tOut (h2 in slot SS): lane = batch m16,
// hid chunk quad*16..+16; shfl_xor(16,32) sums the 4 quads. Uses ep_hold
// (= eps[tOut], prefetched). All role0 lanes end with zn.
#define HEAD(tOut, SS)                                                        \
    {                                                                         \
        const f16* h2p = HB(SS, 2) + m16 * HSTR + quad * 16;                  \
        f16x8 ha = *(const f16x8*)h2p;                                        \
        f16x8 hc = *(const f16x8*)(h2p + 8);                                  \
        float sm = 0.f, sa = 0.f;                                             \
        _Pragma("unroll")                                                     \
        for (int i = 0; i < 4; ++i) {                                         \
            _Pragma("unroll")                                                 \
            for (int j = 0; j < 4; ++j) {                                     \
                float hv = (i < 2) ? (float)ha[i * 4 + j]                     \
                                   : (float)hc[(i - 2) * 4 + j];              \
                sm = fmaf(hv, wmv4[i][j], sm);                                \
                sa = fmaf(hv, wav4[i][j], sa);                                \
            }                                                                 \
        }                                                                     \
        sm += __shfl_xor(sm, 16, 64); sm += __shfl_xor(sm, 32, 64);           \
        sa += __shfl_xor(sa, 16, 64); sa += __shfl_xor(sa, 32, 64);           \
        float mo = (sm + bmv) * vf;                                           \
        float ao = softplusf(sa + bav) * vf;                                  \
        float zs = fmaf(ao, ep_hold, mo);                                     \
        if (tid < 16) out[(size_t)(bg + m16) * TD + (tOut)] = zs;             \
        zn = zs * rvf;                                                        \
    }

    // Step t: slot sc = t&3, prev spv = (t-1)&3 (t=0 -> 3 = encoder exit).
    // Phase A: role0 head(t-1)[h2 spv] + L0(t) [h0 spv -> h0 sc];
    //          role1/2 pre-read recurrent h1/h2 spv into hfa/hfb.
    // Phase B: role1 L1(t) [h0 sc + held -> h1 sc].
    // Phase C: role2 L2(t) [h1 sc + held -> h2 sc].
    for (int t = 0; t < TD; ++t) {
        const int sc  = t & 3;
        const int spv = (t + 3) & 3;
        RBAR;   // previous step's writes (or encoder exit) visible
        {
            f32x4 a0, a1, a2, a3;
            if (role == 0) {
                if (t > 0) {
                    HEAD(t - 1, spv);
                    ep_hold = eps[(size_t)(bg + m16) * TD + t];
                }
                f16x8 af;
                af[0] = (f16)zn;
#pragma unroll
                for (int j = 0; j < 7; ++j) af[1 + j] = (f16)dxr[j];
                const f16* h0p = HB(spv, 0) + aoff;
                f16x8 s0 = *(const f16x8*)h0p;
                f16x8 s1 = *(const f16x8*)(h0p + 32);
                MM_R(a, af, 0);
                MM_RACC(a, s0, 1);
                MM_RACC(a, s1, 2);
                CELL(a, 0, sc);
                if (t + 1 < TD) {
#pragma unroll
                    for (int j = 0; j < 7; ++j)
                        dxr[j] = dec_x[((size_t)(bg + m16) * TD + (t + 1)) * 7 + j];
                }
            } else if (role == 1) {
                const f16* p = HB(spv, 1) + aoff;    // h1(t-1)
                hfa = *(const f16x8*)p;
                hfb = *(const f16x8*)(p + 32);
            } else {
                const f16* p = HB(spv, 2) + aoff;    // h2(t-1)
                hfa = *(const f16x8*)p;
                hfb = *(const f16x8*)(p + 32);
            }
        }
        RBAR;   // h0(t) visible
        if (role == 1) {
            f32x4 a0, a1, a2, a3;
            const f16* h0p = HB(sc, 0) + aoff;
            f16x8 s0 = *(const f16x8*)h0p;
            f16x8 s1 = *(const f16x8*)(h0p + 32);
            MM_R(a, s0, 0);
            MM_RACC(a, s1, 1);
            MM_RACC(a, hfa, 2);
            MM_RACC(a, hfb, 3);
            CELL(a, 1, sc);
        }
        RBAR;   // h1(t) visible
        if (role == 2) {
            f32x4 a0, a1, a2, a3;
            const f16* h1p = HB(sc, 1) + aoff;
            f16x8 s0 = *(const f16x8*)h1p;
            f16x8 s1 = *(const f16x8*)(h1p + 32);
            MM_R(a, s0, 0);
            MM_RACC(a, s1, 1);
            MM_RACC(a, hfa, 2);
            MM_RACC(a, hfb, 3);
            CELL(a, 2, sc);
        }
    }
    RBAR;   // h2(TD-1) visible
    if (role == 0) { HEAD(TD - 1, (TD - 1) & 3); }

#undef RBAR
#undef PRIO_UP
#undef PRIO_DN
#undef HB
#undef MFMA16
#undef MM_R
#undef MM_RACC
#undef CELL
#undef ROUND
#undef HEAD
}

extern "C" void kernel_launch(void* const* d_in, const int* in_sizes, int n_in,
                              void* d_out, int out_size, void* d_ws, size_t ws_size,
                              hipStream_t stream) {
    const float* enc_x = (const float*)d_in[0];
    const float* enc_z = (const float*)d_in[1];
    const float* dec_x = (const float*)d_in[2];
    const float* v     = (const float*)d_in[3];
    const float* eps   = (const float*)d_in[4];
    const float* Wih0  = (const float*)d_in[5];
    const float* Whh0  = (const float*)d_in[6];
    const float* b0    = (const float*)d_in[7];
    const float* Wih1  = (const float*)d_in[8];
    const float* Whh1  = (const float*)d_in[9];
    const float* b1    = (const float*)d_in[10];
    const float* Wih2  = (const float*)d_in[11];
    const float* Whh2  = (const float*)d_in[12];
    const float* b2    = (const float*)d_in[13];
    const float* w_m   = (const float*)d_in[14];
    const float* b_m   = (const float*)d_in[15];
    const float* w_a   = (const float*)d_in[16];
    const float* b_a   = (const float*)d_in[17];
    float* out = (float*)d_out;
    f16*   pk  = (f16*)d_ws;

    pack_kernel<<<384, 256, 0, stream>>>(Wih0, Whh0, Wih1, Whh1, Wih2, Whh2, pk);
    lstm_kernel<<<NWG, 768, 0, stream>>>(enc_x, enc_z, dec_x, v, eps, pk,
                                         b0, b1, b2, w_m, b_m, w_a, b_a, out);
}